// Round 14
// baseline (295.325 us; speedup 1.0000x reference)
//
#include <hip/hip_runtime.h>

// Attention_6219112645023 — fp32 in / fp32 out, bf16 internal compute (MFMA).
// B=2, T=2048, DIM=2048, NH=32, NKV=8, HD=64. Causal GQA + RoPE + projections.
// Pipeline: cvt5 -> qkv_gemm8 -> transpose_v -> flash attn -> O gemm.
// R11/R13/R16: 128x128 2-phase DBUF core (gemm_out keeps it), XOR swizzle
//   (conflicts=0), counted vmcnt, 2-D L2-aware XCD regions. BEST total 288.2.
// R14/R17 lesson: global->reg operand fetch needs whole-line lane coverage.
// R15 lesson: splitting prefetch without phase structure halves hiding dist.
// R19 lesson: scalar LDS scatter = bank-conflict disaster.
// R20: attn denominator on MFMA pipe (kept; neutral, simpler epilogue).
// R21: qkv on m201-style 4-phase 256^2 schedule (the documented lever past
// the 2-phase ~670 TF ceiling — m233/m218/m201):
//   per K-tile: [issue slot0 of t+1] vmcnt(2) barrier (publish t)
//   then 4 phases: {ds_read subtile | issue 2 glds t+1 -> barrier ->
//   lgkmcnt(0) -> setprio 16 MFMA -> barrier}. One counted vmcnt per tile,
//   in-flight never < 2; per-phase barriers convoy 8 waves (ds_read of one
//   group overlaps MFMA of another). Geometry/swizzle/RoPE/C-write verbatim
//   from R10 (correctness-proven at 256^2). Grid 192 blocks (accepted).

typedef unsigned short u16;
typedef __attribute__((ext_vector_type(8))) short bf16x8;  // 8 bf16 in 4 VGPRs
typedef __attribute__((ext_vector_type(4))) float f32x4;
typedef __attribute__((ext_vector_type(4))) unsigned short u16x4;

constexpr int T_SEQ = 2048;
constexpr int DIMC  = 2048;
constexpr int NHEAD = 32;
constexpr int HDIM  = 64;
constexpr int KVDIM = 512;   // NKV * HDIM
constexpr int BATCH = 2;

__device__ __forceinline__ u16 f2bf(float f) {
    union { float f; unsigned int i; } v; v.f = f;
    unsigned int r = v.i + 0x7FFFu + ((v.i >> 16) & 1u);   // RNE
    return (u16)(r >> 16);
}

// pack two f32 -> (bf16 lo = e0, bf16 hi = e1), truncating (P in [0,1]).
__device__ __forceinline__ unsigned int pack2_bf16(float e0, float e1) {
    return __builtin_amdgcn_perm(__float_as_uint(e1), __float_as_uint(e0),
                                 0x07060302u);
}

typedef __attribute__((address_space(1))) unsigned int as1_uint;
typedef __attribute__((address_space(3))) unsigned int as3_uint;
__device__ __forceinline__ void glds16(const u16* g, u16* l) {
    // async global->LDS, 16B/lane; LDS dest = wave-uniform base + lane*16
    __builtin_amdgcn_global_load_lds((as1_uint*)(u16*)g, (as3_uint*)l, 16, 0, 0);
}

// ===========================================================================
// Fused fp32->bf16 convert of all 5 inputs (one launch).
// ===========================================================================
__global__ __launch_bounds__(256) void cvt5(const float* __restrict__ x,
                                            const float* __restrict__ wq,
                                            const float* __restrict__ wk,
                                            const float* __restrict__ wv,
                                            const float* __restrict__ wo,
                                            u16* __restrict__ xb,  u16* __restrict__ wqb,
                                            u16* __restrict__ wkb, u16* __restrict__ wvb,
                                            u16* __restrict__ wob) {
    constexpr int E0 = BATCH * T_SEQ * DIMC;          // 8388608
    constexpr int E1 = E0 + DIMC * DIMC;              // +4194304
    constexpr int E2 = E1 + KVDIM * DIMC;             // +1048576
    constexpr int E3 = E2 + KVDIM * DIMC;             // +1048576
    constexpr int E4 = E3 + DIMC * DIMC;              // 18874368 total
    for (int i = (blockIdx.x * 256 + threadIdx.x) * 4; i < E4; i += gridDim.x * 1024) {
        const float* s; u16* d; int off;
        if (i < E0)      { s = x;  d = xb;  off = 0;  }
        else if (i < E1) { s = wq; d = wqb; off = E0; }
        else if (i < E2) { s = wk; d = wkb; off = E1; }
        else if (i < E3) { s = wv; d = wvb; off = E2; }
        else             { s = wo; d = wob; off = E3; }
        f32x4 v = *(const f32x4*)(s + (i - off));
        u16x4 o;
        #pragma unroll
        for (int e = 0; e < 4; ++e) o[e] = f2bf(v[e]);
        *(u16x4*)(d + (i - off)) = o;
    }
}

// ===========================================================================
// QKV projection, R21: 256x256 tile, BK=64, 512 threads (8 waves, 2M x 4N),
// m201-style 4-phase schedule. LDS 128 KiB (2 dbuf x (A 256x64 + B 256x64)).
// Swizzle (conflicts=0, R10-proven): (row,col) at elem row*64 + (col ^
// ((row&7)*8)); glds SOURCE col pre-swizzled 8*((L&7)^(L>>3)), linear dest.
// Staging slots s=0..3: A rows wid*8+sr+64s, B rows colBase+wid*8+sr+64s,
// LDS chunk (wid+8s)*512. Slot s of tile t+1 issued: s=0 at t top (after
// t-1's last phase barrier retired all reads of that buf), s=1..3 inside
// phases p=0..2. One vmcnt(2) per tile (t's 8 drained, t+1 slot0 flying).
// Phases p=(q2,mh): bw[4] read at mh=0 and held; af[4] per phase; barrier,
// lgkmcnt(0)+sched_barrier (rule #18), setprio(1), 16 MFMA, barrier.
// ===========================================================================
__global__ __launch_bounds__(512, 1) void qkv_gemm8(const u16* __restrict__ xb,
                                                    const u16* __restrict__ wqb,
                                                    const u16* __restrict__ wkb,
                                                    const u16* __restrict__ wvb,
                                                    u16* __restrict__ Qb,
                                                    u16* __restrict__ Kb,
                                                    u16* __restrict__ Vb) {
    __shared__ __align__(16) u16 Ash[2][256 * 64];   // 64 KiB
    __shared__ __align__(16) u16 Bsh[2][256 * 64];   // 64 KiB

    // grid (12,16) -> 192 blocks; XCD region = 8 rows x 3 cols (W slab 3 MB
    // L2-resident), bijective: 8 XCDs x 24.
    const int flat = blockIdx.y * 12 + blockIdx.x;
    const int xcd  = flat & 7;
    const int idx  = flat >> 3;              // 0..23
    const int row  = (xcd >> 2) * 8 + idx / 3;   // 0..15
    const int ct   = (xcd & 3) * 3 + idx % 3;    // 0..11
    const int rowBase = row * 256;

    const u16* W; u16* C; int colBase, N; bool rope;
    if (ct < 8)       { W = wqb; C = Qb; colBase = ct * 256;        N = DIMC;  rope = true; }
    else if (ct < 10) { W = wkb; C = Kb; colBase = (ct - 8) * 256;  N = KVDIM; rope = true; }
    else              { W = wvb; C = Vb; colBase = (ct - 10) * 256; N = KVDIM; rope = false; }

    const int tid  = threadIdx.x;
    const int lane = tid & 63;
    const int wid  = tid >> 6;           // 0..7
    const int quad = lane >> 4;
    const int ln   = lane & 15;
    const int wr   = wid >> 2;           // 0..1  (128-row half)
    const int wc   = wid & 3;            // 0..3  (64-col quarter)

    const int sr = lane >> 3;
    const int sc = 8 * ((lane & 7) ^ sr);
    const u16* aS = xb + (size_t)(rowBase + wid * 8 + sr) * DIMC + sc;
    const u16* bS = W  + (size_t)(colBase + wid * 8 + sr) * DIMC + sc;

    f32x4 acc[8][4] = {};
    constexpr int NT = DIMC / 64;        // 32
    const int swz = (ln & 7) * 8;

    // prologue: tile 0, all 4 slots (8 glds/thread)
    #pragma unroll
    for (int s = 0; s < 4; ++s) {
        glds16(aS + (size_t)(s * 64) * DIMC, &Ash[0][(wid + 8 * s) * 512]);
        glds16(bS + (size_t)(s * 64) * DIMC, &Bsh[0][(wid + 8 * s) * 512]);
    }

    for (int t = 0; t < NT; ++t) {
        const int cb = t & 1;
        const bool pf = (t + 1 < NT);
        const size_t ko = (size_t)(t + 1) * 64;
        u16* An = &Ash[cb ^ 1][0];
        u16* Bn = &Bsh[cb ^ 1][0];

        // slot 0 of t+1 into cb^1 (its readers retired at t-1's last phase
        // barrier), then counted wait: t's 8 done, t+1's 2 stay flying.
        if (pf) {
            glds16(aS + ko, An + wid * 512);
            glds16(bS + ko, Bn + wid * 512);
            __builtin_amdgcn_sched_barrier(0);
            __asm__ __volatile__("s_waitcnt vmcnt(2)" ::: "memory");
        } else {
            __asm__ __volatile__("s_waitcnt vmcnt(0)" ::: "memory");   // epilogue
        }
        __builtin_amdgcn_sched_barrier(0);
        __builtin_amdgcn_s_barrier();        // tile t published

        const u16* Ap = &Ash[cb][0];
        const u16* Bp = &Bsh[cb][0];

        bf16x8 bw[4];
        #pragma unroll
        for (int p = 0; p < 4; ++p) {
            const int q2 = p >> 1;           // K-half
            const int mh = p & 1;            // M-half of wave tile
            if (mh == 0) {                   // bw shared across the mh pair
                #pragma unroll
                for (int n = 0; n < 4; ++n)
                    bw[n] = *(const bf16x8*)(Bp + (wc * 64 + n * 16 + ln) * 64
                                                + ((q2 * 32 + quad * 8) ^ swz));
            }
            bf16x8 af[4];
            #pragma unroll
            for (int m = 0; m < 4; ++m)
                af[m] = *(const bf16x8*)(Ap + (wr * 128 + (mh * 4 + m) * 16 + ln) * 64
                                            + ((q2 * 32 + quad * 8) ^ swz));
            if (pf && p < 3) {               // slots 1..3 of t+1
                const int s = p + 1;
                glds16(aS + ko + (size_t)(s * 64) * DIMC, An + (wid + 8 * s) * 512);
                glds16(bS + ko + (size_t)(s * 64) * DIMC, Bn + (wid + 8 * s) * 512);
            }
            __builtin_amdgcn_sched_barrier(0);
            __builtin_amdgcn_s_barrier();    // convoy: all waves issued phase ops
            __asm__ __volatile__("s_waitcnt lgkmcnt(0)" ::: "memory");
            __builtin_amdgcn_sched_barrier(0);
            __builtin_amdgcn_s_setprio(1);
            #pragma unroll
            for (int m = 0; m < 4; ++m) {
                #pragma unroll
                for (int n = 0; n < 4; ++n)
                    acc[mh * 4 + m][n] = __builtin_amdgcn_mfma_f32_16x16x32_bf16(
                                             af[m], bw[n], acc[mh * 4 + m][n], 0, 0, 0);
            }
            __builtin_amdgcn_s_setprio(0);
            __builtin_amdgcn_s_barrier();    // phase end (read-retire point)
        }
    }

    if (rope) {
        // head-local d = n*16+ln (64-col wave span = one head);
        // pairs (d, d+32) -> (acc[m][n], acc[m][n+2]).  [R10-verbatim]
        #pragma unroll
        for (int n = 0; n < 2; ++n) {
            const int d = n * 16 + ln;
            const float invrev = exp2f(-(float)d * (13.287712379549449f / 32.0f))
                                 * 0.15915494309189535f;   // /2pi
            #pragma unroll
            for (int m = 0; m < 8; ++m) {
                #pragma unroll
                for (int r = 0; r < 4; ++r) {
                    const int tt = (rowBase + wr * 128 + m * 16 + quad * 4 + r) & (T_SEQ - 1);
                    float rev = (float)tt * invrev;
                    float fr = rev - floorf(rev);
                    float sn = __builtin_amdgcn_sinf(fr);
                    float cs = __builtin_amdgcn_cosf(fr);
                    float a0 = acc[m][n][r], a2 = acc[m][n + 2][r];
                    acc[m][n][r]     = a0 * cs - a2 * sn;
                    acc[m][n + 2][r] = a2 * cs + a0 * sn;
                }
            }
        }
    }

    #pragma unroll
    for (int m = 0; m < 8; ++m) {
        const int mrow = rowBase + wr * 128 + m * 16 + quad * 4;
        #pragma unroll
        for (int n = 0; n < 4; ++n) {
            const int col = colBase + wc * 64 + n * 16 + ln;
            #pragma unroll
            for (int r = 0; r < 4; ++r)
                C[(size_t)(mrow + r) * N + col] = f2bf(acc[m][n][r]);
        }
    }
}

// ===========================================================================
// DBUF GEMM core (R13 schedule) — kept for gemm_out: 128x128 tile, BK=64,
// 4 waves, 64 KiB LDS, counted vmcnt(8), XOR swizzle (conflicts=0).
// ===========================================================================
template <bool OUTF32>
__device__ __forceinline__ void dgemm_core(const u16* __restrict__ A,
                                           const u16* __restrict__ W,
                                           void* __restrict__ Cv,
                                           int rowBase, int colBase,
                                           int N, int K) {
    __shared__ __align__(16) u16 Ash[2][128 * 64];   // 32 KiB
    __shared__ __align__(16) u16 Bsh[2][128 * 64];   // 32 KiB

    const int tid  = threadIdx.x;
    const int lane = tid & 63;
    const int w    = tid >> 6;           // 0..3
    const int quad = lane >> 4;
    const int ln   = lane & 15;
    const int wm   = (w >> 1) * 64;
    const int wn   = (w & 1) * 64;

    const int sr = lane >> 3;            // 0..7
    const int sc = 8 * ((lane & 7) ^ sr);
    const u16* aS = A + (size_t)(rowBase + w * 8 + sr) * K + sc;
    const u16* bS = W + (size_t)(colBase + w * 8 + sr) * K + sc;

    f32x4 acc[4][4] = {};
    const int NT = K / 64;
    const int swz = (ln & 7) * 8;

    #pragma unroll
    for (int r = 0; r < 4; ++r) {
        glds16(aS + (size_t)(r * 32) * K, &Ash[0][(w + 4 * r) * 512]);
        glds16(bS + (size_t)(r * 32) * K, &Bsh[0][(w + 4 * r) * 512]);
    }

    for (int t = 0; t < NT; ++t) {
        const int cb = t & 1;
        __builtin_amdgcn_s_barrier();          // reads of buf cb^1 complete
        __builtin_amdgcn_sched_barrier(0);

        if (t + 1 < NT) {
            const size_t ko = (size_t)(t + 1) * 64;
            u16* An = &Ash[cb ^ 1][0];
            u16* Bn = &Bsh[cb ^ 1][0];
            #pragma unroll
            for (int r = 0; r < 4; ++r) {
                glds16(aS + ko + (size_t)(r * 32) * K, An + (w + 4 * r) * 512);
                glds16(bS + ko + (size_t)(r * 32) * K, Bn + (w + 4 * r) * 512);
            }
            __builtin_amdgcn_sched_barrier(0);
            __asm__ __volatile__("s_waitcnt vmcnt(8)" ::: "memory");  // t done, t+1 flying
        } else {
            __asm__ __volatile__("s_waitcnt vmcnt(0)" ::: "memory");  // epilogue drain
        }
        __builtin_amdgcn_sched_barrier(0);
        __builtin_amdgcn_s_barrier();          // tile t published

        const u16* Ap = &Ash[cb][0];
        const u16* Bp = &Bsh[cb][0];
        #pragma unroll
        for (int q2 = 0; q2 < 2; ++q2) {
            bf16x8 bwf[4];
            #pragma unroll
            for (int n = 0; n < 4; ++n)
                bwf[n] = *(const bf16x8*)(Bp + (wn + n * 16 + ln) * 64
                                             + ((q2 * 32 + quad * 8) ^ swz));
            __builtin_amdgcn_s_setprio(1);
            #pragma unroll
            for (int m = 0; m < 4; ++m) {
                bf16x8 af = *(const bf16x8*)(Ap + (wm + m * 16 + ln) * 64
                                                + ((q2 * 32 + quad * 8) ^ swz));
                #pragma unroll
                for (int n = 0; n < 4; ++n)
                    acc[m][n] = __builtin_amdgcn_mfma_f32_16x16x32_bf16(af, bwf[n], acc[m][n], 0, 0, 0);
            }
            __builtin_amdgcn_s_setprio(0);
        }
    }

    #pragma unroll
    for (int i = 0; i < 4; ++i) {
        int mrow = rowBase + wm + i * 16 + quad * 4;
        #pragma unroll
        for (int j = 0; j < 4; ++j) {
            int n = colBase + wn + j * 16 + ln;
            #pragma unroll
            for (int r = 0; r < 4; ++r) {
                if constexpr (OUTF32)
                    ((float*)Cv)[(size_t)(mrow + r) * N + n] = acc[i][j][r];
                else
                    ((u16*)Cv)[(size_t)(mrow + r) * N + n] = f2bf(acc[i][j][r]);
            }
        }
    }
}

// O-projection: 16 col-tiles x 32 row-tiles = 512 blocks.
// R16 XCD region: 16 rows x 4 cols per XCD (W slab 2 MB L2-resident).
__global__ __launch_bounds__(256, 2) void gemm_out(const u16* __restrict__ A,
                                                   const u16* __restrict__ W,
                                                   float* __restrict__ C) {
    const int flat = blockIdx.y * 16 + blockIdx.x;
    const int xcd  = flat & 7;
    const int idx  = flat >> 3;          // 0..63
    const int row  = (xcd >> 2) * 16 + (idx >> 2);
    const int col  = (xcd & 3) * 4 + (idx & 3);
    dgemm_core<true>(A, W, C, row * 128, col * 128, DIMC, DIMC);
}

// ===========================================================================
// V [B*T][KVDIM] -> Vt [B][KVDIM][T]
// ===========================================================================
__global__ __launch_bounds__(256) void transpose_v(const u16* __restrict__ V,
                                                   u16* __restrict__ Vt) {
    __shared__ __align__(16) u16 tile[32][33];
    const int x = threadIdx.x & 31;
    const int y = threadIdx.x >> 5;
    const int tok0 = blockIdx.y * 32;
    const int c0   = blockIdx.x * 32;
    #pragma unroll
    for (int yy = 0; yy < 32; yy += 8)
        tile[y + yy][x] = V[(size_t)(tok0 + y + yy) * KVDIM + c0 + x];
    __syncthreads();
    const int b  = tok0 >> 11;
    const int t0 = tok0 & (T_SEQ - 1);
    #pragma unroll
    for (int yy = 0; yy < 32; yy += 8)
        Vt[(size_t)(b * KVDIM + c0 + y + yy) * T_SEQ + t0 + x] = tile[x][y + yy];
}

// ===========================================================================
// Flash attention. grid = (16, NH, B), block = 256 (4 waves).
// R8: swapped QK^T (D[key][q]) + key->slot permutation
//   slot(k) = 32*(k>>5) + 8*((k>>2)&3) + 4*((k>>4)&1) + (k&3)
// R9/R13: reg-prefetch staging, K/V dbuf LDS, ONE raw barrier per kt.
// R20: denominator on MFMA pipe (lsv = mfma(P, ones)) — output already in
// O-epilogue layout; kills VALU adds + epilogue shfl reduction.
// ===========================================================================
__global__ __launch_bounds__(256) void attn(const u16* __restrict__ Q,
                                            const u16* __restrict__ Kx,
                                            const u16* __restrict__ Vt,
                                            u16* __restrict__ O) {
    __shared__ __align__(16) u16 Ks[2][64][72];    // [buf][key][dim]
    __shared__ __align__(16) u16 Vs[2][64][72];    // [buf][dim][slot]

    const int tid  = threadIdx.x;
    const int lane = tid & 63;
    const int w    = tid >> 6;
    const int quad = lane >> 4;
    const int ln   = lane & 15;
    const int h    = blockIdx.y;
    const int b    = blockIdx.z;
    const int kvh  = h >> 2;

    const int srow = tid >> 2;           // 0..63
    const int c    = tid & 3;
    const int scol = c * 16;             // token group base (16 tokens)
    const int vsb  = 32 * (c >> 1) + 4 * (c & 1);
    const u16* kbase = Kx + (size_t)(b * T_SEQ + srow) * KVDIM + kvh * HDIM + scol;
    const u16* vbase = Vt + (size_t)(b * KVDIM + kvh * HDIM + srow) * T_SEQ;

    const float K1 = 0.125f * 1.4426950408889634f;   // scale * log2(e)
    const float K2 = 8.0f * 1.4426950408889634f;     // M0 * log2(e)

    union { unsigned int u[4]; bf16x8 v; } ones;
    ones.u[0] = 0x3F803F80u; ones.u[1] = 0x3F803F80u;
    ones.u[2] = 0x3F803F80u; ones.u[3] = 0x3F803F80u;

    #pragma unroll
    for (int phase = 0; phase < 2; ++phase) {
        const int qt = phase ? (31 - (int)blockIdx.x) : (int)blockIdx.x;
        const int qr0 = qt * 64 + w * 16;

        const u16* qp = Q + (size_t)(b * T_SEQ + qr0 + ln) * DIMC + h * HDIM + quad * 8;
        const bf16x8 bq0 = *(const bf16x8*)qp;        // B-operand: col = q = ln
        const bf16x8 bq1 = *(const bf16x8*)(qp + 32);

        f32x4 o[4] = {};
        f32x4 lsv = {};                   // denominator, O-epilogue layout

        bf16x8 kra = *(const bf16x8*)kbase;
        bf16x8 krb = *(const bf16x8*)(kbase + 8);
        bf16x8 vra = *(const bf16x8*)(vbase + scol);
        bf16x8 vrb = *(const bf16x8*)(vbase + scol + 8);

        for (int kt = 0; kt <= qt; ++kt) {
            const int cb = kt & 1;

            *(bf16x8*)&Ks[cb][srow][scol]     = kra;
            *(bf16x8*)&Ks[cb][srow][scol + 8] = krb;
            {   // V staging, slot-permuted: 4x ds_write_b64
                union { bf16x8 v; u16x4 h4[2]; } ua, ub;
                ua.v = vra; ub.v = vrb;
                *(u16x4*)&Vs[cb][srow][vsb]      = ua.h4[0];
                *(u16x4*)&Vs[cb][srow][vsb + 8]  = ua.h4[1];
                *(u16x4*)&Vs[cb][srow][vsb + 16] = ub.h4[0];
                *(u16x4*)&Vs[cb][srow][vsb + 24] = ub.h4[1];
            }

            if (kt < qt) {
                const size_t ko = (size_t)(kt + 1) * 64;
                kra = *(const bf16x8*)(kbase + ko * KVDIM);
                krb = *(const bf16x8*)(kbase + ko * KVDIM + 8);
                vra = *(const bf16x8*)(vbase + ko + scol);
                vrb = *(const bf16x8*)(vbase + ko + scol + 8);
            }

            __asm__ __volatile__("s_waitcnt lgkmcnt(0)" ::: "memory");
            __builtin_amdgcn_s_barrier();

            f32x4 s[4];
            __builtin_amdgcn_s_setprio(1);
            #pragma unroll
            for (int st = 0; st < 4; ++st) {
                f32x4 z = {};
                s[st] = __builtin_amdgcn_mfma_f32_16x16x32_bf16(
                            *(const bf16x8*)&Ks[cb][st * 16 + ln][quad * 8], bq0, z, 0, 0, 0);
                s[st] = __builtin_amdgcn_mfma_f32_16x16x32_bf16(
                            *(const bf16x8*)&Ks[cb][st * 16 + ln][32 + quad * 8], bq1, s[st], 0, 0, 0);
            }
            __builtin_amdgcn_s_setprio(0);

            unsigned int pk[8];
            if (kt != qt) {
                #pragma unroll
                for (int st = 0; st < 4; ++st) {
                    float e0 = exp2f(fmaf(s[st][0], K1, -K2));
                    float e1 = exp2f(fmaf(s[st][1], K1, -K2));
                    float e2 = exp2f(fmaf(s[st][2], K1, -K2));
                    float e3 = exp2f(fmaf(s[st][3], K1, -K2));
                    pk[2 * st]     = pack2_bf16(e0, e1);
                    pk[2 * st + 1] = pack2_bf16(e2, e3);
                }
            } else {
                const int thr = w * 16 + ln;            // q local in 64-block
                #pragma unroll
                for (int st = 0; st < 4; ++st) {
                    float e[4];
                    #pragma unroll
                    for (int r = 0; r < 4; ++r) {
                        const int key = st * 16 + quad * 4 + r;
                        e[r] = (key > thr) ? 0.0f : exp2f(fmaf(s[st][r], K1, -K2));
                    }
                    pk[2 * st]     = pack2_bf16(e[0], e[1]);
                    pk[2 * st + 1] = pack2_bf16(e[2], e[3]);
                }
            }

            union { unsigned int u[4]; bf16x8 v; } a0, a1;
            a0.u[0] = pk[0]; a0.u[1] = pk[1]; a0.u[2] = pk[2]; a0.u[3] = pk[3];
            a1.u[0] = pk[4]; a1.u[1] = pk[5]; a1.u[2] = pk[6]; a1.u[3] = pk[7];

            __builtin_amdgcn_s_setprio(1);
            lsv = __builtin_amdgcn_mfma_f32_16x16x32_bf16(a0.v, ones.v, lsv, 0, 0, 0);
            lsv = __builtin_amdgcn_mfma_f32_16x16x32_bf16(a1.v, ones.v, lsv, 0, 0, 0);
            #pragma unroll
            for (int t = 0; t < 4; ++t) {
                o[t] = __builtin_amdgcn_mfma_f32_16x16x32_bf16(
                           a0.v, *(const bf16x8*)&Vs[cb][t * 16 + ln][quad * 8], o[t], 0, 0, 0);
                o[t] = __builtin_amdgcn_mfma_f32_16x16x32_bf16(
                           a1.v, *(const bf16x8*)&Vs[cb][t * 16 + ln][32 + quad * 8], o[t], 0, 0, 0);
            }
            __builtin_amdgcn_s_setprio(0);
        }

        #pragma unroll
        for (int r = 0; r < 4; ++r) {
            const float inv = 1.0f / lsv[r];
            size_t obase = (size_t)(b * T_SEQ + qr0 + quad * 4 + r) * DIMC + h * HDIM;
            #pragma unroll
            for (int t = 0; t < 4; ++t)
                O[obase + t * 16 + ln] = f2bf(o[t][r] * inv);
        }

        __syncthreads();   // phase boundary
    }
}

// ===========================================================================
extern "C" void kernel_launch(void* const* d_in, const int* in_sizes, int n_in,
                              void* d_out, int out_size, void* d_ws, size_t ws_size,
                              hipStream_t stream) {
    const float* x  = (const float*)d_in[0];
    const float* wq = (const float*)d_in[1];
    const float* wk = (const float*)d_in[2];
    const float* wv = (const float*)d_in[3];
    const float* wo = (const float*)d_in[4];
    float* out = (float*)d_out;

    char* ws = (char*)d_ws;
    constexpr size_t MB = 1024 * 1024;
    u16* Qb  = (u16*)(ws);             // 16 MB [4096][2048]
    u16* Kb  = (u16*)(ws + 16 * MB);   //  4 MB [4096][512]
    u16* Vb  = (u16*)(ws + 20 * MB);   //  4 MB [4096][512]
    u16* Vtb = (u16*)(ws + 24 * MB);   //  4 MB [2][512][2048]
    u16* AOb = (u16*)(ws + 28 * MB);   // 16 MB [4096][2048]  (aliases xb)
    u16* xb  = AOb;                    // x dead before attn writes AOb
    u16* wqb = (u16*)(ws + 44 * MB);   //  8 MB
    u16* wkb = (u16*)(ws + 52 * MB);   //  2 MB
    u16* wvb = (u16*)(ws + 54 * MB);   //  2 MB
    u16* wob = (u16*)(ws + 56 * MB);   //  8 MB
    const int M = BATCH * T_SEQ;       // 4096

    hipLaunchKernelGGL(cvt5, dim3(2048), dim3(256), 0, stream,
                       x, wq, wk, wv, wo, xb, wqb, wkb, wvb, wob);
    hipLaunchKernelGGL(qkv_gemm8, dim3(12, M / 256), dim3(512), 0, stream,
                       xb, wqb, wkb, wvb, Qb, Kb, Vb);
    hipLaunchKernelGGL(transpose_v, dim3(KVDIM / 32, M / 32), dim3(256), 0, stream, Vb, Vtb);
    hipLaunchKernelGGL(attn, dim3(16, NHEAD, BATCH), dim3(256), 0, stream,
                       Qb, Kb, Vtb, AOb);
    hipLaunchKernelGGL(gemm_out, dim3(DIMC / 128, M / 128), dim3(256), 0, stream,
                       AOb, wob, out);
}

// Round 15
// 288.022 us; speedup vs baseline: 1.0254x; 1.0254x over previous
//
#include <hip/hip_runtime.h>

// Attention_6219112645023 — fp32 in / fp32 out, bf16 internal compute (MFMA).
// B=2, T=2048, DIM=2048, NH=32, NKV=8, HD=64. Causal GQA + RoPE + projections.
// Pipeline: cvt5 -> qkv_gemm8 -> transpose_v -> flash attn -> O gemm.
// R11/R13/R16: 128x128 2-phase DBUF core (gemm_out keeps it), XOR swizzle
//   (conflicts=0), counted vmcnt, 2-D L2-aware XCD regions.
// R14/R17 lesson: global->reg operand fetch needs whole-line lane coverage.
// R15 lesson: splitting prefetch without phase structure halves hiding dist.
// R19 lesson: scalar LDS scatter = bank-conflict disaster.
// R20: attn denominator on MFMA pipe (kept; simpler epilogue).
// R21: qkv on m201-style 4-phase 256^2 schedule — qkv 77.2 -> 72.7 us
//   (MfmaUtil 28, FETCH -24%), but total 295.3 vs R20's 289.6 with all
//   other kernels byte-identical => rest-of-pipeline noise band is +-5-8 us.
// R22: VERBATIM REPLICATE of R21 (methodology rule #13: deltas inside the
//   noise band need replication, not reaction). If total >=293 again, next
//   round reverts qkv to the R16 core and declares the plateau.

typedef unsigned short u16;
typedef __attribute__((ext_vector_type(8))) short bf16x8;  // 8 bf16 in 4 VGPRs
typedef __attribute__((ext_vector_type(4))) float f32x4;
typedef __attribute__((ext_vector_type(4))) unsigned short u16x4;

constexpr int T_SEQ = 2048;
constexpr int DIMC  = 2048;
constexpr int NHEAD = 32;
constexpr int HDIM  = 64;
constexpr int KVDIM = 512;   // NKV * HDIM
constexpr int BATCH = 2;

__device__ __forceinline__ u16 f2bf(float f) {
    union { float f; unsigned int i; } v; v.f = f;
    unsigned int r = v.i + 0x7FFFu + ((v.i >> 16) & 1u);   // RNE
    return (u16)(r >> 16);
}

// pack two f32 -> (bf16 lo = e0, bf16 hi = e1), truncating (P in [0,1]).
__device__ __forceinline__ unsigned int pack2_bf16(float e0, float e1) {
    return __builtin_amdgcn_perm(__float_as_uint(e1), __float_as_uint(e0),
                                 0x07060302u);
}

typedef __attribute__((address_space(1))) unsigned int as1_uint;
typedef __attribute__((address_space(3))) unsigned int as3_uint;
__device__ __forceinline__ void glds16(const u16* g, u16* l) {
    // async global->LDS, 16B/lane; LDS dest = wave-uniform base + lane*16
    __builtin_amdgcn_global_load_lds((as1_uint*)(u16*)g, (as3_uint*)l, 16, 0, 0);
}

// ===========================================================================
// Fused fp32->bf16 convert of all 5 inputs (one launch).
// ===========================================================================
__global__ __launch_bounds__(256) void cvt5(const float* __restrict__ x,
                                            const float* __restrict__ wq,
                                            const float* __restrict__ wk,
                                            const float* __restrict__ wv,
                                            const float* __restrict__ wo,
                                            u16* __restrict__ xb,  u16* __restrict__ wqb,
                                            u16* __restrict__ wkb, u16* __restrict__ wvb,
                                            u16* __restrict__ wob) {
    constexpr int E0 = BATCH * T_SEQ * DIMC;          // 8388608
    constexpr int E1 = E0 + DIMC * DIMC;              // +4194304
    constexpr int E2 = E1 + KVDIM * DIMC;             // +1048576
    constexpr int E3 = E2 + KVDIM * DIMC;             // +1048576
    constexpr int E4 = E3 + DIMC * DIMC;              // 18874368 total
    for (int i = (blockIdx.x * 256 + threadIdx.x) * 4; i < E4; i += gridDim.x * 1024) {
        const float* s; u16* d; int off;
        if (i < E0)      { s = x;  d = xb;  off = 0;  }
        else if (i < E1) { s = wq; d = wqb; off = E0; }
        else if (i < E2) { s = wk; d = wkb; off = E1; }
        else if (i < E3) { s = wv; d = wvb; off = E2; }
        else             { s = wo; d = wob; off = E3; }
        f32x4 v = *(const f32x4*)(s + (i - off));
        u16x4 o;
        #pragma unroll
        for (int e = 0; e < 4; ++e) o[e] = f2bf(v[e]);
        *(u16x4*)(d + (i - off)) = o;
    }
}

// ===========================================================================
// QKV projection, R21: 256x256 tile, BK=64, 512 threads (8 waves, 2M x 4N),
// m201-style 4-phase schedule. LDS 128 KiB (2 dbuf x (A 256x64 + B 256x64)).
// Swizzle (conflicts=0): (row,col) at elem row*64 + (col ^ ((row&7)*8));
// glds SOURCE col pre-swizzled 8*((L&7)^(L>>3)), linear dest.
// Staging slots s=0..3; slot s of tile t+1 issued: s=0 at t top, s=1..3
// inside phases p=0..2. One vmcnt(2) per tile; in-flight never < 2.
// Phases p=(q2,mh): bw[4] read at mh=0 and held; af[4] per phase; barrier,
// lgkmcnt(0)+sched_barrier (rule #18), setprio(1), 16 MFMA, barrier.
// ===========================================================================
__global__ __launch_bounds__(512, 1) void qkv_gemm8(const u16* __restrict__ xb,
                                                    const u16* __restrict__ wqb,
                                                    const u16* __restrict__ wkb,
                                                    const u16* __restrict__ wvb,
                                                    u16* __restrict__ Qb,
                                                    u16* __restrict__ Kb,
                                                    u16* __restrict__ Vb) {
    __shared__ __align__(16) u16 Ash[2][256 * 64];   // 64 KiB
    __shared__ __align__(16) u16 Bsh[2][256 * 64];   // 64 KiB

    // grid (12,16) -> 192 blocks; XCD region = 8 rows x 3 cols (W slab 3 MB
    // L2-resident), bijective: 8 XCDs x 24.
    const int flat = blockIdx.y * 12 + blockIdx.x;
    const int xcd  = flat & 7;
    const int idx  = flat >> 3;              // 0..23
    const int row  = (xcd >> 2) * 8 + idx / 3;   // 0..15
    const int ct   = (xcd & 3) * 3 + idx % 3;    // 0..11
    const int rowBase = row * 256;

    const u16* W; u16* C; int colBase, N; bool rope;
    if (ct < 8)       { W = wqb; C = Qb; colBase = ct * 256;        N = DIMC;  rope = true; }
    else if (ct < 10) { W = wkb; C = Kb; colBase = (ct - 8) * 256;  N = KVDIM; rope = true; }
    else              { W = wvb; C = Vb; colBase = (ct - 10) * 256; N = KVDIM; rope = false; }

    const int tid  = threadIdx.x;
    const int lane = tid & 63;
    const int wid  = tid >> 6;           // 0..7
    const int quad = lane >> 4;
    const int ln   = lane & 15;
    const int wr   = wid >> 2;           // 0..1  (128-row half)
    const int wc   = wid & 3;            // 0..3  (64-col quarter)

    const int sr = lane >> 3;
    const int sc = 8 * ((lane & 7) ^ sr);
    const u16* aS = xb + (size_t)(rowBase + wid * 8 + sr) * DIMC + sc;
    const u16* bS = W  + (size_t)(colBase + wid * 8 + sr) * DIMC + sc;

    f32x4 acc[8][4] = {};
    constexpr int NT = DIMC / 64;        // 32
    const int swz = (ln & 7) * 8;

    // prologue: tile 0, all 4 slots (8 glds/thread)
    #pragma unroll
    for (int s = 0; s < 4; ++s) {
        glds16(aS + (size_t)(s * 64) * DIMC, &Ash[0][(wid + 8 * s) * 512]);
        glds16(bS + (size_t)(s * 64) * DIMC, &Bsh[0][(wid + 8 * s) * 512]);
    }

    for (int t = 0; t < NT; ++t) {
        const int cb = t & 1;
        const bool pf = (t + 1 < NT);
        const size_t ko = (size_t)(t + 1) * 64;
        u16* An = &Ash[cb ^ 1][0];
        u16* Bn = &Bsh[cb ^ 1][0];

        // slot 0 of t+1 into cb^1 (its readers retired at t-1's last phase
        // barrier), then counted wait: t's 8 done, t+1's 2 stay flying.
        if (pf) {
            glds16(aS + ko, An + wid * 512);
            glds16(bS + ko, Bn + wid * 512);
            __builtin_amdgcn_sched_barrier(0);
            __asm__ __volatile__("s_waitcnt vmcnt(2)" ::: "memory");
        } else {
            __asm__ __volatile__("s_waitcnt vmcnt(0)" ::: "memory");   // epilogue
        }
        __builtin_amdgcn_sched_barrier(0);
        __builtin_amdgcn_s_barrier();        // tile t published

        const u16* Ap = &Ash[cb][0];
        const u16* Bp = &Bsh[cb][0];

        bf16x8 bw[4];
        #pragma unroll
        for (int p = 0; p < 4; ++p) {
            const int q2 = p >> 1;           // K-half
            const int mh = p & 1;            // M-half of wave tile
            if (mh == 0) {                   // bw shared across the mh pair
                #pragma unroll
                for (int n = 0; n < 4; ++n)
                    bw[n] = *(const bf16x8*)(Bp + (wc * 64 + n * 16 + ln) * 64
                                                + ((q2 * 32 + quad * 8) ^ swz));
            }
            bf16x8 af[4];
            #pragma unroll
            for (int m = 0; m < 4; ++m)
                af[m] = *(const bf16x8*)(Ap + (wr * 128 + (mh * 4 + m) * 16 + ln) * 64
                                            + ((q2 * 32 + quad * 8) ^ swz));
            if (pf && p < 3) {               // slots 1..3 of t+1
                const int s = p + 1;
                glds16(aS + ko + (size_t)(s * 64) * DIMC, An + (wid + 8 * s) * 512);
                glds16(bS + ko + (size_t)(s * 64) * DIMC, Bn + (wid + 8 * s) * 512);
            }
            __builtin_amdgcn_sched_barrier(0);
            __builtin_amdgcn_s_barrier();    // convoy: all waves issued phase ops
            __asm__ __volatile__("s_waitcnt lgkmcnt(0)" ::: "memory");
            __builtin_amdgcn_sched_barrier(0);
            __builtin_amdgcn_s_setprio(1);
            #pragma unroll
            for (int m = 0; m < 4; ++m) {
                #pragma unroll
                for (int n = 0; n < 4; ++n)
                    acc[mh * 4 + m][n] = __builtin_amdgcn_mfma_f32_16x16x32_bf16(
                                             af[m], bw[n], acc[mh * 4 + m][n], 0, 0, 0);
            }
            __builtin_amdgcn_s_setprio(0);
            __builtin_amdgcn_s_barrier();    // phase end (read-retire point)
        }
    }

    if (rope) {
        // head-local d = n*16+ln (64-col wave span = one head);
        // pairs (d, d+32) -> (acc[m][n], acc[m][n+2]).
        #pragma unroll
        for (int n = 0; n < 2; ++n) {
            const int d = n * 16 + ln;
            const float invrev = exp2f(-(float)d * (13.287712379549449f / 32.0f))
                                 * 0.15915494309189535f;   // /2pi
            #pragma unroll
            for (int m = 0; m < 8; ++m) {
                #pragma unroll
                for (int r = 0; r < 4; ++r) {
                    const int tt = (rowBase + wr * 128 + m * 16 + quad * 4 + r) & (T_SEQ - 1);
                    float rev = (float)tt * invrev;
                    float fr = rev - floorf(rev);
                    float sn = __builtin_amdgcn_sinf(fr);
                    float cs = __builtin_amdgcn_cosf(fr);
                    float a0 = acc[m][n][r], a2 = acc[m][n + 2][r];
                    acc[m][n][r]     = a0 * cs - a2 * sn;
                    acc[m][n + 2][r] = a2 * cs + a0 * sn;
                }
            }
        }
    }

    #pragma unroll
    for (int m = 0; m < 8; ++m) {
        const int mrow = rowBase + wr * 128 + m * 16 + quad * 4;
        #pragma unroll
        for (int n = 0; n < 4; ++n) {
            const int col = colBase + wc * 64 + n * 16 + ln;
            #pragma unroll
            for (int r = 0; r < 4; ++r)
                C[(size_t)(mrow + r) * N + col] = f2bf(acc[m][n][r]);
        }
    }
}

// ===========================================================================
// DBUF GEMM core (R13 schedule) — kept for gemm_out: 128x128 tile, BK=64,
// 4 waves, 64 KiB LDS, counted vmcnt(8), XOR swizzle (conflicts=0).
// ===========================================================================
template <bool OUTF32>
__device__ __forceinline__ void dgemm_core(const u16* __restrict__ A,
                                           const u16* __restrict__ W,
                                           void* __restrict__ Cv,
                                           int rowBase, int colBase,
                                           int N, int K) {
    __shared__ __align__(16) u16 Ash[2][128 * 64];   // 32 KiB
    __shared__ __align__(16) u16 Bsh[2][128 * 64];   // 32 KiB

    const int tid  = threadIdx.x;
    const int lane = tid & 63;
    const int w    = tid >> 6;           // 0..3
    const int quad = lane >> 4;
    const int ln   = lane & 15;
    const int wm   = (w >> 1) * 64;
    const int wn   = (w & 1) * 64;

    const int sr = lane >> 3;            // 0..7
    const int sc = 8 * ((lane & 7) ^ sr);
    const u16* aS = A + (size_t)(rowBase + w * 8 + sr) * K + sc;
    const u16* bS = W + (size_t)(colBase + w * 8 + sr) * K + sc;

    f32x4 acc[4][4] = {};
    const int NT = K / 64;
    const int swz = (ln & 7) * 8;

    #pragma unroll
    for (int r = 0; r < 4; ++r) {
        glds16(aS + (size_t)(r * 32) * K, &Ash[0][(w + 4 * r) * 512]);
        glds16(bS + (size_t)(r * 32) * K, &Bsh[0][(w + 4 * r) * 512]);
    }

    for (int t = 0; t < NT; ++t) {
        const int cb = t & 1;
        __builtin_amdgcn_s_barrier();          // reads of buf cb^1 complete
        __builtin_amdgcn_sched_barrier(0);

        if (t + 1 < NT) {
            const size_t ko = (size_t)(t + 1) * 64;
            u16* An = &Ash[cb ^ 1][0];
            u16* Bn = &Bsh[cb ^ 1][0];
            #pragma unroll
            for (int r = 0; r < 4; ++r) {
                glds16(aS + ko + (size_t)(r * 32) * K, An + (w + 4 * r) * 512);
                glds16(bS + ko + (size_t)(r * 32) * K, Bn + (w + 4 * r) * 512);
            }
            __builtin_amdgcn_sched_barrier(0);
            __asm__ __volatile__("s_waitcnt vmcnt(8)" ::: "memory");  // t done, t+1 flying
        } else {
            __asm__ __volatile__("s_waitcnt vmcnt(0)" ::: "memory");  // epilogue drain
        }
        __builtin_amdgcn_sched_barrier(0);
        __builtin_amdgcn_s_barrier();          // tile t published

        const u16* Ap = &Ash[cb][0];
        const u16* Bp = &Bsh[cb][0];
        #pragma unroll
        for (int q2 = 0; q2 < 2; ++q2) {
            bf16x8 bwf[4];
            #pragma unroll
            for (int n = 0; n < 4; ++n)
                bwf[n] = *(const bf16x8*)(Bp + (wn + n * 16 + ln) * 64
                                             + ((q2 * 32 + quad * 8) ^ swz));
            __builtin_amdgcn_s_setprio(1);
            #pragma unroll
            for (int m = 0; m < 4; ++m) {
                bf16x8 af = *(const bf16x8*)(Ap + (wm + m * 16 + ln) * 64
                                                + ((q2 * 32 + quad * 8) ^ swz));
                #pragma unroll
                for (int n = 0; n < 4; ++n)
                    acc[m][n] = __builtin_amdgcn_mfma_f32_16x16x32_bf16(af, bwf[n], acc[m][n], 0, 0, 0);
            }
            __builtin_amdgcn_s_setprio(0);
        }
    }

    #pragma unroll
    for (int i = 0; i < 4; ++i) {
        int mrow = rowBase + wm + i * 16 + quad * 4;
        #pragma unroll
        for (int j = 0; j < 4; ++j) {
            int n = colBase + wn + j * 16 + ln;
            #pragma unroll
            for (int r = 0; r < 4; ++r) {
                if constexpr (OUTF32)
                    ((float*)Cv)[(size_t)(mrow + r) * N + n] = acc[i][j][r];
                else
                    ((u16*)Cv)[(size_t)(mrow + r) * N + n] = f2bf(acc[i][j][r]);
            }
        }
    }
}

// O-projection: 16 col-tiles x 32 row-tiles = 512 blocks.
// R16 XCD region: 16 rows x 4 cols per XCD (W slab 2 MB L2-resident).
__global__ __launch_bounds__(256, 2) void gemm_out(const u16* __restrict__ A,
                                                   const u16* __restrict__ W,
                                                   float* __restrict__ C) {
    const int flat = blockIdx.y * 16 + blockIdx.x;
    const int xcd  = flat & 7;
    const int idx  = flat >> 3;          // 0..63
    const int row  = (xcd >> 2) * 16 + (idx >> 2);
    const int col  = (xcd & 3) * 4 + (idx & 3);
    dgemm_core<true>(A, W, C, row * 128, col * 128, DIMC, DIMC);
}

// ===========================================================================
// V [B*T][KVDIM] -> Vt [B][KVDIM][T]
// ===========================================================================
__global__ __launch_bounds__(256) void transpose_v(const u16* __restrict__ V,
                                                   u16* __restrict__ Vt) {
    __shared__ __align__(16) u16 tile[32][33];
    const int x = threadIdx.x & 31;
    const int y = threadIdx.x >> 5;
    const int tok0 = blockIdx.y * 32;
    const int c0   = blockIdx.x * 32;
    #pragma unroll
    for (int yy = 0; yy < 32; yy += 8)
        tile[y + yy][x] = V[(size_t)(tok0 + y + yy) * KVDIM + c0 + x];
    __syncthreads();
    const int b  = tok0 >> 11;
    const int t0 = tok0 & (T_SEQ - 1);
    #pragma unroll
    for (int yy = 0; yy < 32; yy += 8)
        Vt[(size_t)(b * KVDIM + c0 + y + yy) * T_SEQ + t0 + x] = tile[x][y + yy];
}

// ===========================================================================
// Flash attention. grid = (16, NH, B), block = 256 (4 waves).
// R8: swapped QK^T (D[key][q]) + key->slot permutation
//   slot(k) = 32*(k>>5) + 8*((k>>2)&3) + 4*((k>>4)&1) + (k&3)
// R9/R13: reg-prefetch staging, K/V dbuf LDS, ONE raw barrier per kt.
// R20: denominator on MFMA pipe (lsv = mfma(P, ones)) — output already in
// O-epilogue layout; kills VALU adds + epilogue shfl reduction.
// ===========================================================================
__global__ __launch_bounds__(256) void attn(const u16* __restrict__ Q,
                                            const u16* __restrict__ Kx,
                                            const u16* __restrict__ Vt,
                                            u16* __restrict__ O) {
    __shared__ __align__(16) u16 Ks[2][64][72];    // [buf][key][dim]
    __shared__ __align__(16) u16 Vs[2][64][72];    // [buf][dim][slot]

    const int tid  = threadIdx.x;
    const int lane = tid & 63;
    const int w    = tid >> 6;
    const int quad = lane >> 4;
    const int ln   = lane & 15;
    const int h    = blockIdx.y;
    const int b    = blockIdx.z;
    const int kvh  = h >> 2;

    const int srow = tid >> 2;           // 0..63
    const int c    = tid & 3;
    const int scol = c * 16;             // token group base (16 tokens)
    const int vsb  = 32 * (c >> 1) + 4 * (c & 1);
    const u16* kbase = Kx + (size_t)(b * T_SEQ + srow) * KVDIM + kvh * HDIM + scol;
    const u16* vbase = Vt + (size_t)(b * KVDIM + kvh * HDIM + srow) * T_SEQ;

    const float K1 = 0.125f * 1.4426950408889634f;   // scale * log2(e)
    const float K2 = 8.0f * 1.4426950408889634f;     // M0 * log2(e)

    union { unsigned int u[4]; bf16x8 v; } ones;
    ones.u[0] = 0x3F803F80u; ones.u[1] = 0x3F803F80u;
    ones.u[2] = 0x3F803F80u; ones.u[3] = 0x3F803F80u;

    #pragma unroll
    for (int phase = 0; phase < 2; ++phase) {
        const int qt = phase ? (31 - (int)blockIdx.x) : (int)blockIdx.x;
        const int qr0 = qt * 64 + w * 16;

        const u16* qp = Q + (size_t)(b * T_SEQ + qr0 + ln) * DIMC + h * HDIM + quad * 8;
        const bf16x8 bq0 = *(const bf16x8*)qp;        // B-operand: col = q = ln
        const bf16x8 bq1 = *(const bf16x8*)(qp + 32);

        f32x4 o[4] = {};
        f32x4 lsv = {};                   // denominator, O-epilogue layout

        bf16x8 kra = *(const bf16x8*)kbase;
        bf16x8 krb = *(const bf16x8*)(kbase + 8);
        bf16x8 vra = *(const bf16x8*)(vbase + scol);
        bf16x8 vrb = *(const bf16x8*)(vbase + scol + 8);

        for (int kt = 0; kt <= qt; ++kt) {
            const int cb = kt & 1;

            *(bf16x8*)&Ks[cb][srow][scol]     = kra;
            *(bf16x8*)&Ks[cb][srow][scol + 8] = krb;
            {   // V staging, slot-permuted: 4x ds_write_b64
                union { bf16x8 v; u16x4 h4[2]; } ua, ub;
                ua.v = vra; ub.v = vrb;
                *(u16x4*)&Vs[cb][srow][vsb]      = ua.h4[0];
                *(u16x4*)&Vs[cb][srow][vsb + 8]  = ua.h4[1];
                *(u16x4*)&Vs[cb][srow][vsb + 16] = ub.h4[0];
                *(u16x4*)&Vs[cb][srow][vsb + 24] = ub.h4[1];
            }

            if (kt < qt) {
                const size_t ko = (size_t)(kt + 1) * 64;
                kra = *(const bf16x8*)(kbase + ko * KVDIM);
                krb = *(const bf16x8*)(kbase + ko * KVDIM + 8);
                vra = *(const bf16x8*)(vbase + ko + scol);
                vrb = *(const bf16x8*)(vbase + ko + scol + 8);
            }

            __asm__ __volatile__("s_waitcnt lgkmcnt(0)" ::: "memory");
            __builtin_amdgcn_s_barrier();

            f32x4 s[4];
            __builtin_amdgcn_s_setprio(1);
            #pragma unroll
            for (int st = 0; st < 4; ++st) {
                f32x4 z = {};
                s[st] = __builtin_amdgcn_mfma_f32_16x16x32_bf16(
                            *(const bf16x8*)&Ks[cb][st * 16 + ln][quad * 8], bq0, z, 0, 0, 0);
                s[st] = __builtin_amdgcn_mfma_f32_16x16x32_bf16(
                            *(const bf16x8*)&Ks[cb][st * 16 + ln][32 + quad * 8], bq1, s[st], 0, 0, 0);
            }
            __builtin_amdgcn_s_setprio(0);

            unsigned int pk[8];
            if (kt != qt) {
                #pragma unroll
                for (int st = 0; st < 4; ++st) {
                    float e0 = exp2f(fmaf(s[st][0], K1, -K2));
                    float e1 = exp2f(fmaf(s[st][1], K1, -K2));
                    float e2 = exp2f(fmaf(s[st][2], K1, -K2));
                    float e3 = exp2f(fmaf(s[st][3], K1, -K2));
                    pk[2 * st]     = pack2_bf16(e0, e1);
                    pk[2 * st + 1] = pack2_bf16(e2, e3);
                }
            } else {
                const int thr = w * 16 + ln;            // q local in 64-block
                #pragma unroll
                for (int st = 0; st < 4; ++st) {
                    float e[4];
                    #pragma unroll
                    for (int r = 0; r < 4; ++r) {
                        const int key = st * 16 + quad * 4 + r;
                        e[r] = (key > thr) ? 0.0f : exp2f(fmaf(s[st][r], K1, -K2));
                    }
                    pk[2 * st]     = pack2_bf16(e[0], e[1]);
                    pk[2 * st + 1] = pack2_bf16(e[2], e[3]);
                }
            }

            union { unsigned int u[4]; bf16x8 v; } a0, a1;
            a0.u[0] = pk[0]; a0.u[1] = pk[1]; a0.u[2] = pk[2]; a0.u[3] = pk[3];
            a1.u[0] = pk[4]; a1.u[1] = pk[5]; a1.u[2] = pk[6]; a1.u[3] = pk[7];

            __builtin_amdgcn_s_setprio(1);
            lsv = __builtin_amdgcn_mfma_f32_16x16x32_bf16(a0.v, ones.v, lsv, 0, 0, 0);
            lsv = __builtin_amdgcn_mfma_f32_16x16x32_bf16(a1.v, ones.v, lsv, 0, 0, 0);
            #pragma unroll
            for (int t = 0; t < 4; ++t) {
                o[t] = __builtin_amdgcn_mfma_f32_16x16x32_bf16(
                           a0.v, *(const bf16x8*)&Vs[cb][t * 16 + ln][quad * 8], o[t], 0, 0, 0);
                o[t] = __builtin_amdgcn_mfma_f32_16x16x32_bf16(
                           a1.v, *(const bf16x8*)&Vs[cb][t * 16 + ln][32 + quad * 8], o[t], 0, 0, 0);
            }
            __builtin_amdgcn_s_setprio(0);
        }

        #pragma unroll
        for (int r = 0; r < 4; ++r) {
            const float inv = 1.0f / lsv[r];
            size_t obase = (size_t)(b * T_SEQ + qr0 + quad * 4 + r) * DIMC + h * HDIM;
            #pragma unroll
            for (int t = 0; t < 4; ++t)
                O[obase + t * 16 + ln] = f2bf(o[t][r] * inv);
        }

        __syncthreads();   // phase boundary
    }
}

// ===========================================================================
extern "C" void kernel_launch(void* const* d_in, const int* in_sizes, int n_in,
                              void* d_out, int out_size, void* d_ws, size_t ws_size,
                              hipStream_t stream) {
    const float* x  = (const float*)d_in[0];
    const float* wq = (const float*)d_in[1];
    const float* wk = (const float*)d_in[2];
    const float* wv = (const float*)d_in[3];
    const float* wo = (const float*)d_in[4];
    float* out = (float*)d_out;

    char* ws = (char*)d_ws;
    constexpr size_t MB = 1024 * 1024;
    u16* Qb  = (u16*)(ws);             // 16 MB [4096][2048]
    u16* Kb  = (u16*)(ws + 16 * MB);   //  4 MB [4096][512]
    u16* Vb  = (u16*)(ws + 20 * MB);   //  4 MB [4096][512]
    u16* Vtb = (u16*)(ws + 24 * MB);   //  4 MB [2][512][2048]
    u16* AOb = (u16*)(ws + 28 * MB);   // 16 MB [4096][2048]  (aliases xb)
    u16* xb  = AOb;                    // x dead before attn writes AOb
    u16* wqb = (u16*)(ws + 44 * MB);   //  8 MB
    u16* wkb = (u16*)(ws + 52 * MB);   //  2 MB
    u16* wvb = (u16*)(ws + 54 * MB);   //  2 MB
    u16* wob = (u16*)(ws + 56 * MB);   //  8 MB
    const int M = BATCH * T_SEQ;       // 4096

    hipLaunchKernelGGL(cvt5, dim3(2048), dim3(256), 0, stream,
                       x, wq, wk, wv, wo, xb, wqb, wkb, wvb, wob);
    hipLaunchKernelGGL(qkv_gemm8, dim3(12, M / 256), dim3(512), 0, stream,
                       xb, wqb, wkb, wvb, Qb, Kb, Vb);
    hipLaunchKernelGGL(transpose_v, dim3(KVDIM / 32, M / 32), dim3(256), 0, stream, Vb, Vtb);
    hipLaunchKernelGGL(attn, dim3(16, NHEAD, BATCH), dim3(256), 0, stream,
                       Qb, Kb, Vtb, AOb);
    hipLaunchKernelGGL(gemm_out, dim3(DIMC / 128, M / 128), dim3(256), 0, stream,
                       AOb, wob, out);
}